// Round 1
// baseline (161.782 us; speedup 1.0000x reference)
//
#include <hip/hip_runtime.h>
#include <stdint.h>

#define NDIM  256   // accumulator width
#define NFEAT 640   // piece features per sample
#define NROWS 641   // 640 features + 1 king bias row
#define SG    8     // slots processed together per group
#define GSTRIDE 4   // base groups per (king,part); blocks loop gi += GSTRIDE
#define MAXRPB 320  // max rows per block (rp=2 case)
#define CPB   4     // samples per combine block
#define MAXSLOTS 2048  // LDS slot-list capacity (B<=1024); larger B falls back to mono

typedef unsigned short ushort4v __attribute__((ext_vector_type(4)));
typedef unsigned short ushort8v __attribute__((ext_vector_type(8)));

// ============================ fused gather (bucketing inlined) ============================
// Each block owns (king k = bid&63, row-part p, base group g0) and loops groups gi += GSTRIDE.
// Bucketing: wave 0 rebuilds the ordered slot list for king k via a ballot scan over kp
// (nslots <= 2048 -> 32 ballot steps, kp is L2-resident; ~1 us). partial is indexed by RAW
// slot id, so combine needs no slot_pos indirection and the bucket kernel is gone.
struct GatherLds {
    int flags[2];                      // raww, rawpp (per-block inline detect)
    int cnt;                           // #slots for this king
    unsigned short list[MAXSLOTS];     // ordered slot ids of this king (4 KB)
    int samp[SG];                      // sample ids of current group
    int slotid[SG];                    // raw slot ids of current group
    unsigned mask[MAXRPB];             // per-row activity bits for the SG slots
    unsigned red[4][SG][NDIM / 2];     // packed u16 pairs, per-wave partials (16 KB)
};

template<bool RAWW, bool RAWPP>
__device__ __forceinline__ void gather_body(
    const void* __restrict__ ppv, const void* __restrict__ Wv,
    unsigned short* __restrict__ partial, int nslots, int rp, GatherLds& sh)
{
    const int bid = blockIdx.x;
    const int k = bid & 63;            // bid%8 == k%8 -> XCD pinning for W[k] L2 residency
    const int rest = bid >> 6;
    const int p = rest & (rp - 1);     // row part (rp is 2 or 4)
    const int g0 = rest >> (rp == 4 ? 2 : 1);
    const int t = threadIdx.x, l = t & 63, g = t >> 6;

    const int cnt = sh.cnt;
    const int rpb = NFEAT / rp;
    const int r0 = p * rpb;
    const int rows_per_wave = rpb / 4;
    const int lbeg = g * rows_per_wave;
    const char* Wk = (const char*)Wv + (size_t)k * NROWS * NDIM * (RAWW ? 2 : 4);

    for (int gi = g0; gi * SG < cnt; gi += GSTRIDE) {
        const int base = gi * SG;
        const int ns = min(SG, cnt - base);
        const unsigned emask = (1u << ns) - 1u;

        if (t < SG) {
            const int s = sh.list[base + min(t, ns - 1)];
            sh.slotid[t] = s;
            sh.samp[t] = s >> 1;       // s = 2*sample + side
        }
        __syncthreads();

        // ---- per-row activity masks for rows [r0, r0+rpb) ----
        for (int r = t; r < rpb; r += 256) {
            unsigned mm = 0;
            #pragma unroll
            for (int i = 0; i < SG; ++i) {
                const int s = sh.samp[i];
                int v;
                if (RAWPP) v = ((const uint8_t*)ppv)[(size_t)s * NFEAT + r0 + r];
                else       v = ((const int*)ppv)[(size_t)s * NFEAT + r0 + r];
                mm |= (v != 0 ? 1u : 0u) << i;
            }
            sh.mask[r] = mm & emask;
        }
        __syncthreads();

        // ---- row loop: one row load, packed-u16 adds into active slots (mod 2^16 exact) ----
        ushort4v acc[SG];
        #pragma unroll
        for (int i = 0; i < SG; ++i) acc[i] = (ushort4v)0;

        #pragma unroll 2
        for (int rr = 0; rr < rows_per_wave; ++rr) {
            const int lr = lbeg + rr;
            unsigned mm = sh.mask[lr];
            mm = __builtin_amdgcn_readfirstlane(mm);   // wave-uniform -> scalar branches
            ushort4v w;
            if (RAWW) {
                w = *(const ushort4v*)(Wk + (size_t)(r0 + lr) * 512 + (size_t)l * 8);
            } else {
                const int4 u = *(const int4*)(Wk + (size_t)(r0 + lr) * 1024 + (size_t)l * 16);
                w.x = (unsigned short)u.x; w.y = (unsigned short)u.y;
                w.z = (unsigned short)u.z; w.w = (unsigned short)u.w;
            }
            #pragma unroll
            for (int i = 0; i < SG; ++i)
                if (mm & (1u << i)) acc[i] += w;       // 2x v_pk_add_u16
        }

        // ---- cross-wave reduce in LDS, write u16 partials at raw slot id ----
        #pragma unroll
        for (int i = 0; i < SG; ++i)
            *(ushort4v*)&sh.red[g][i][2 * l] = acc[i];
        __syncthreads();

        const int i = t >> 5;              // slot 0..7
        const int j4 = (t & 31) * 4;       // uint index within slot
        if (i < ns) {
            ushort8v sv = *(const ushort8v*)&sh.red[0][i][j4];
            #pragma unroll
            for (int g2 = 1; g2 < 4; ++g2) sv += *(const ushort8v*)&sh.red[g2][i][j4];
            *(ushort8v*)&partial[((size_t)p * nslots + sh.slotid[i]) * NDIM + (size_t)(t & 31) * 8] = sv;
        }
        __syncthreads();                   // red/mask/samp reused next group
    }
}

__global__ __launch_bounds__(256, 4) void nnue_gather(
    const void* __restrict__ pp, const int* __restrict__ kp,
    const void* __restrict__ W, unsigned short* __restrict__ partial,
    int* __restrict__ ws, int nslots, int rp)
{
    __shared__ GatherLds sh;
    const int t = threadIdx.x, l = t & 63, g = t >> 6;
    const int k = blockIdx.x & 63;

    if (blockIdx.x == 0 && t == 0) { ws[0] = 0; ws[3] = 0; }   // sum + ticket for combine

    if (t == 0) {  // inline layout detect (int16-raw vs int32-expanded; bool vs int32)
        int raww = 0, rawpp = 0;
        const int* W32 = (const int*)W;
        const int* pp32 = (const int*)pp;
        for (int i = 0; i < 16; ++i) {
            const int v = W32[i];
            if (v > 32767 || v < -32768) raww = 1;
            const int u = pp32[i];
            if (u != 0 && u != 1) rawpp = 1;
        }
        sh.flags[0] = raww; sh.flags[1] = rawpp;
    }
    if (g == 0) {  // wave 0: ordered slot list for king k via ballot scan
        int cnt = 0;
        for (int c = 0; c < nslots; c += 64) {
            const int s = c + l;
            const bool f = (s < nslots) && (kp[s] == k);
            const unsigned long long m = __ballot(f);
            if (f) sh.list[cnt + (int)__popcll(m & ((1ull << l) - 1ull))] = (unsigned short)s;
            cnt += (int)__popcll(m);
        }
        if (l == 0) sh.cnt = cnt;
    }
    __syncthreads();

    const int raww = sh.flags[0], rawpp = sh.flags[1];
    if (raww) {
        if (rawpp) gather_body<true,  true >(pp, W, partial, nslots, rp, sh);
        else       gather_body<true,  false>(pp, W, partial, nslots, rp, sh);
    } else {
        if (rawpp) gather_body<false, true >(pp, W, partial, nslots, rp, sh);
        else       gather_body<false, false>(pp, W, partial, nslots, rp, sh);
    }
}

// ============================ combine + FC layers + inline finalize ============================
struct CombineLds {
    alignas(16) int8_t x[NDIM];
    int fc[256];
    alignas(4) int8_t x2[32];
    int flags;
};

template<bool RAWW>
__device__ __forceinline__ void combine_body(
    const unsigned short* __restrict__ partial, const int* __restrict__ kp,
    const void* __restrict__ Wv, const void* __restrict__ ibv,
    const void* __restrict__ w1v, const int* __restrict__ b1,
    const void* __restrict__ w2v, const int* __restrict__ b2,
    const void* __restrict__ owv, const int* __restrict__ ob,
    int* __restrict__ ws, int* __restrict__ out,
    int nslots, int B, int rp, CombineLds& sh)
{
    const int t = threadIdx.x;
    int blocksum = 0;

    for (int ss = 0; ss < CPB; ++ss) {
        const int b = blockIdx.x * CPB + ss;
        if (b >= B) break;
        const int k0 = kp[2 * b + 0];
        const int k1 = kp[2 * b + 1];
        {
            unsigned tot = 0;  // u16 arithmetic carried in u32; truncate at end
            for (int pi = 0; pi < rp; ++pi) {
                tot += partial[((size_t)pi * nslots + 2 * b + 0) * NDIM + t];
                tot += partial[((size_t)pi * nslots + 2 * b + 1) * NDIM + t];
            }
            if (RAWW) {
                const uint16_t* Wq = (const uint16_t*)Wv;
                tot += Wq[((size_t)k0 * NROWS + NFEAT) * NDIM + t];
                tot += Wq[((size_t)k1 * NROWS + NFEAT) * NDIM + t];
                tot += ((const uint16_t*)ibv)[t];
            } else {
                const int* Wq = (const int*)Wv;
                tot += (unsigned)Wq[((size_t)k0 * NROWS + NFEAT) * NDIM + t];
                tot += (unsigned)Wq[((size_t)k1 * NROWS + NFEAT) * NDIM + t];
                tot += (unsigned)((const int*)ibv)[t];
            }
            int v = (int)(int16_t)(uint16_t)tot;   // int16 wraparound semantics
            v = v < 0 ? 0 : (v > 127 ? 127 : v);
            sh.x[t] = (int8_t)v;
        }
        __syncthreads();

        // ---- FC1: 32 outputs over concat([x,x]) = fold the two 256-halves of w1 ----
        {
            const int o = t >> 3, part = t & 7;
            int y = 0;
            const uint32_t* xw = (const uint32_t*)sh.x;
            if (RAWW) {
                const uint32_t* w1r = (const uint32_t*)((const char*)w1v + o * 512);
                #pragma unroll
                for (int i = 0; i < 8; ++i) {
                    const int wi = part * 8 + i;
                    const uint32_t xv = xw[wi];
                    const uint32_t wa = w1r[wi];
                    const uint32_t wb = w1r[64 + wi];
                    #pragma unroll
                    for (int jj = 0; jj < 4; ++jj) {
                        const int xj  = (int)((xv >> (8 * jj)) & 0xFFu);
                        const int waj = (int)(int8_t)(uint8_t)(wa >> (8 * jj));
                        const int wbj = (int)(int8_t)(uint8_t)(wb >> (8 * jj));
                        y += xj * (waj + wbj);
                    }
                }
            } else {
                const int* w1r = (const int*)w1v + o * 512;
                #pragma unroll
                for (int i = 0; i < 8; ++i) {
                    const int wi = part * 8 + i;
                    const uint32_t xv = xw[wi];
                    #pragma unroll
                    for (int jj = 0; jj < 4; ++jj) {
                        const int xj = (int)((xv >> (8 * jj)) & 0xFFu);
                        y += xj * (w1r[wi * 4 + jj] + w1r[256 + wi * 4 + jj]);
                    }
                }
            }
            sh.fc[t] = y;
        }
        __syncthreads();

        if (t < 32) {
            int y = b1[t];
            #pragma unroll
            for (int pq = 0; pq < 8; ++pq) y += sh.fc[t * 8 + pq];
            y >>= 6;                                  // floor_divide(y, 64)
            y = y < 0 ? 0 : (y > 127 ? 127 : y);
            sh.x2[t] = (int8_t)y;
        }
        __syncthreads();

        // ---- FC2 + output dot ----
        if (t < 32) {
            int y = b2[t];
            const uint32_t* x2w = (const uint32_t*)sh.x2;
            if (RAWW) {
                const uint32_t* w2r = (const uint32_t*)((const char*)w2v + t * 32);
                #pragma unroll
                for (int i = 0; i < 8; ++i) {
                    const uint32_t xv = x2w[i];
                    const uint32_t wv = w2r[i];
                    #pragma unroll
                    for (int jj = 0; jj < 4; ++jj)
                        y += (int)((xv >> (8 * jj)) & 0xFFu) * (int)(int8_t)(uint8_t)(wv >> (8 * jj));
                }
            } else {
                const int* w2r = (const int*)w2v + t * 32;
                #pragma unroll
                for (int i = 0; i < 8; ++i) {
                    const uint32_t xv = x2w[i];
                    #pragma unroll
                    for (int jj = 0; jj < 4; ++jj)
                        y += (int)((xv >> (8 * jj)) & 0xFFu) * w2r[i * 4 + jj];
                }
            }
            y >>= 6;
            y = y < 0 ? 0 : (y > 127 ? 127 : y);
            const int owx = RAWW ? (int)((const int8_t*)owv)[t] : ((const int*)owv)[t];
            int pr = y * owx;
            #pragma unroll
            for (int off = 16; off > 0; off >>= 1) pr += __shfl_down(pr, off, 32);
            if (t == 0) blocksum += pr;
        }
        __syncthreads();   // sh.x reused next sample
    }

    // ---- one atomic per block, ticket-based inline finalize (last block writes out) ----
    if (t == 0) {
        atomicAdd(&ws[0], blocksum);
        __threadfence();                               // device-scope: order add before ticket
        const int ticket = atomicAdd(&ws[3], 1);
        if (ticket == (int)gridDim.x - 1) {
            const int s = atomicAdd(&ws[0], 0);        // device-scope atomic read
            out[0] = (s + ob[0]) >> 4;                 // floor_divide(s, 16)
        }
    }
}

__global__ __launch_bounds__(256) void nnue_combine(
    const unsigned short* __restrict__ partial, const int* __restrict__ kp,
    const void* __restrict__ W, const void* __restrict__ ib,
    const void* __restrict__ w1, const int* __restrict__ b1,
    const void* __restrict__ w2, const int* __restrict__ b2,
    const void* __restrict__ ow, const int* __restrict__ ob,
    int* __restrict__ ws, int* __restrict__ out, int nslots, int B, int rp)
{
    __shared__ CombineLds sh;
    if (threadIdx.x == 0) {
        int raww = 0;
        const int* W32 = (const int*)W;
        for (int i = 0; i < 16; ++i) {
            const int v = W32[i];
            if (v > 32767 || v < -32768) raww = 1;
        }
        sh.flags = raww;
    }
    __syncthreads();
    if (sh.flags) combine_body<true >(partial, kp, W, ib, w1, b1, w2, b2, ow, ob, ws, out, nslots, B, rp, sh);
    else          combine_body<false>(partial, kp, W, ib, w1, b1, w2, b2, ow, ob, ws, out, nslots, B, rp, sh);
}

__global__ void nnue_finalize(const int* __restrict__ ws, const int* __restrict__ ob,
                              int* __restrict__ out) {
    out[0] = (ws[0] + ob[0]) >> 4;  // floor_divide(s, 16)
}

// ============================ fallback (monolithic, any B / tiny ws) ============================
struct SharedBuf {
    uint8_t pp[NFEAT];
    int     acc[4][NDIM];
    alignas(16) int8_t x[NDIM];
    int     fc[256];
    alignas(4) int8_t x2[32];
    int     list[4][160];
};

__global__ void detect_layout(const int* __restrict__ W32, const int* __restrict__ pp32,
                              int* __restrict__ ws) {
    int raww = 0, rawpp = 0;
    for (int i = 0; i < 16; ++i) {
        const int v = W32[i];
        if (v > 32767 || v < -32768) raww = 1;
        const int u = pp32[i];
        if (u != 0 && u != 1) rawpp = 1;
    }
    ws[0] = 0; ws[1] = raww; ws[2] = rawpp;
}

template<bool RAWW, bool RAWPP>
__device__ __forceinline__ void mono_body(
    const void* __restrict__ ppv, const int* __restrict__ kp,
    const void* __restrict__ Wv,  const void* __restrict__ ibv,
    const void* __restrict__ w1v, const int* __restrict__ b1,
    const void* __restrict__ w2v, const int* __restrict__ b2,
    const void* __restrict__ owv, int* __restrict__ ws, SharedBuf& sh)
{
    const int b = blockIdx.x;
    const int t = threadIdx.x;
    const int l = t & 63;
    const int g = t >> 6;

    if (RAWPP) {
        const uint32_t* src = (const uint32_t*)((const uint8_t*)ppv + (size_t)b * NFEAT);
        if (t < NFEAT / 4) ((uint32_t*)sh.pp)[t] = src[t];
    } else {
        const int* src = (const int*)ppv + (size_t)b * NFEAT;
        for (int i = t; i < NFEAT; i += 256) sh.pp[i] = (uint8_t)(src[i] != 0);
    }
    __syncthreads();

    const int base = g * 160;
    int cnt = 0;
    for (int c = 0; c < 160; c += 64) {
        const int idx = c + l;
        const bool flag = (idx < 160) && (sh.pp[base + idx] != 0);
        const unsigned long long mmask = __ballot(flag);
        const int pos = cnt + (int)__popcll(mmask & ((1ull << l) - 1ull));
        if (flag) sh.list[g][pos] = base + idx;
        cnt += (int)__popcll(mmask);
    }

    const int k0 = kp[b * 2 + 0];
    const int k1 = kp[b * 2 + 1];
    int a0 = 0, a1 = 0, a2 = 0, a3 = 0, a4 = 0, a5 = 0, a6 = 0, a7 = 0;

    if (RAWW) {
        const char* W0 = (const char*)Wv + (size_t)k0 * (NROWS * NDIM * 2);
        const char* W1 = (const char*)Wv + (size_t)k1 * (NROWS * NDIM * 2);
        const int lo = l * 8;
        auto step = [&](int f) {
            const uint2 u0 = *(const uint2*)(W0 + f * 512 + lo);
            const uint2 u1 = *(const uint2*)(W1 + f * 512 + lo);
            a0 += (int)(u0.x & 0xFFFFu); a1 += (int)(u0.x >> 16);
            a2 += (int)(u0.y & 0xFFFFu); a3 += (int)(u0.y >> 16);
            a4 += (int)(u1.x & 0xFFFFu); a5 += (int)(u1.x >> 16);
            a6 += (int)(u1.y & 0xFFFFu); a7 += (int)(u1.y >> 16);
        };
        int j = 0;
        for (; j + 4 <= cnt; j += 4) {
            const int f0 = sh.list[g][j], f1 = sh.list[g][j + 1];
            const int f2 = sh.list[g][j + 2], f3 = sh.list[g][j + 3];
            step(f0); step(f1); step(f2); step(f3);
        }
        for (; j < cnt; ++j) step(sh.list[g][j]);
    } else {
        const char* W0 = (const char*)Wv + (size_t)k0 * (NROWS * NDIM * 4);
        const char* W1 = (const char*)Wv + (size_t)k1 * (NROWS * NDIM * 4);
        const int lo = l * 16;
        auto step = [&](int f) {
            const int4 u0 = *(const int4*)(W0 + f * 1024 + lo);
            const int4 u1 = *(const int4*)(W1 + f * 1024 + lo);
            a0 += u0.x; a1 += u0.y; a2 += u0.z; a3 += u0.w;
            a4 += u1.x; a5 += u1.y; a6 += u1.z; a7 += u1.w;
        };
        int j = 0;
        for (; j + 4 <= cnt; j += 4) {
            const int f0 = sh.list[g][j], f1 = sh.list[g][j + 1];
            const int f2 = sh.list[g][j + 2], f3 = sh.list[g][j + 3];
            step(f0); step(f1); step(f2); step(f3);
        }
        for (; j < cnt; ++j) step(sh.list[g][j]);
    }

    sh.acc[g][4 * l + 0] = a0 + a4;
    sh.acc[g][4 * l + 1] = a1 + a5;
    sh.acc[g][4 * l + 2] = a2 + a6;
    sh.acc[g][4 * l + 3] = a3 + a7;
    __syncthreads();

    {
        const int d = t;
        int tot = sh.acc[0][d] + sh.acc[1][d] + sh.acc[2][d] + sh.acc[3][d];
        int kb0, kb1, ibx;
        if (RAWW) {
            const int16_t* Wq = (const int16_t*)Wv;
            kb0 = Wq[((size_t)k0 * NROWS + NFEAT) * NDIM + d];
            kb1 = Wq[((size_t)k1 * NROWS + NFEAT) * NDIM + d];
            ibx = ((const int16_t*)ibv)[d];
        } else {
            const int* Wq = (const int*)Wv;
            kb0 = Wq[((size_t)k0 * NROWS + NFEAT) * NDIM + d];
            kb1 = Wq[((size_t)k1 * NROWS + NFEAT) * NDIM + d];
            ibx = ((const int*)ibv)[d];
        }
        tot += kb0 + kb1 + ibx;
        int v = (int)(int16_t)(uint16_t)(uint32_t)tot;
        v = v < 0 ? 0 : (v > 127 ? 127 : v);
        sh.x[d] = (int8_t)v;
    }
    __syncthreads();

    {
        const int o = t >> 3, part = t & 7;
        int y = 0;
        const uint32_t* xw = (const uint32_t*)sh.x;
        if (RAWW) {
            const uint32_t* w1r = (const uint32_t*)((const char*)w1v + o * 512);
            #pragma unroll
            for (int i = 0; i < 8; ++i) {
                const int wi = part * 8 + i;
                const uint32_t xv = xw[wi];
                const uint32_t wa = w1r[wi];
                const uint32_t wb = w1r[64 + wi];
                #pragma unroll
                for (int jj = 0; jj < 4; ++jj) {
                    const int xj  = (int)((xv >> (8 * jj)) & 0xFFu);
                    const int waj = (int)(int8_t)(uint8_t)(wa >> (8 * jj));
                    const int wbj = (int)(int8_t)(uint8_t)(wb >> (8 * jj));
                    y += xj * (waj + wbj);
                }
            }
        } else {
            const int* w1r = (const int*)w1v + o * 512;
            #pragma unroll
            for (int i = 0; i < 8; ++i) {
                const int wi = part * 8 + i;
                const uint32_t xv = xw[wi];
                #pragma unroll
                for (int jj = 0; jj < 4; ++jj) {
                    const int xj = (int)((xv >> (8 * jj)) & 0xFFu);
                    y += xj * (w1r[wi * 4 + jj] + w1r[256 + wi * 4 + jj]);
                }
            }
        }
        sh.fc[t] = y;
    }
    __syncthreads();

    if (t < 32) {
        int y = b1[t];
        #pragma unroll
        for (int pq = 0; pq < 8; ++pq) y += sh.fc[t * 8 + pq];
        y >>= 6;
        y = y < 0 ? 0 : (y > 127 ? 127 : y);
        sh.x2[t] = (int8_t)y;
    }
    __syncthreads();

    if (t < 32) {
        int y = b2[t];
        const uint32_t* x2w = (const uint32_t*)sh.x2;
        if (RAWW) {
            const uint32_t* w2r = (const uint32_t*)((const char*)w2v + t * 32);
            #pragma unroll
            for (int i = 0; i < 8; ++i) {
                const uint32_t xv = x2w[i];
                const uint32_t wv = w2r[i];
                #pragma unroll
                for (int jj = 0; jj < 4; ++jj)
                    y += (int)((xv >> (8 * jj)) & 0xFFu) * (int)(int8_t)(uint8_t)(wv >> (8 * jj));
            }
        } else {
            const int* w2r = (const int*)w2v + t * 32;
            #pragma unroll
            for (int i = 0; i < 8; ++i) {
                const uint32_t xv = x2w[i];
                #pragma unroll
                for (int jj = 0; jj < 4; ++jj)
                    y += (int)((xv >> (8 * jj)) & 0xFFu) * w2r[i * 4 + jj];
            }
        }
        y >>= 6;
        y = y < 0 ? 0 : (y > 127 ? 127 : y);
        const int owx = RAWW ? (int)((const int8_t*)owv)[t] : ((const int*)owv)[t];
        int pr = y * owx;
        #pragma unroll
        for (int off = 16; off > 0; off >>= 1) pr += __shfl_down(pr, off, 32);
        if (t == 0) atomicAdd(ws, pr);
    }
}

__global__ __launch_bounds__(256, 4) void nnue_mono(
    const void* __restrict__ pp, const int* __restrict__ kp,
    const void* __restrict__ W,  const void* __restrict__ ib,
    const void* __restrict__ w1, const int* __restrict__ b1,
    const void* __restrict__ w2, const int* __restrict__ b2,
    const void* __restrict__ ow, int* __restrict__ ws)
{
    __shared__ SharedBuf sh;
    const int raww = ws[1], rawpp = ws[2];
    if (raww) {
        if (rawpp) mono_body<true,  true >(pp, kp, W, ib, w1, b1, w2, b2, ow, ws, sh);
        else       mono_body<true,  false>(pp, kp, W, ib, w1, b1, w2, b2, ow, ws, sh);
    } else {
        if (rawpp) mono_body<false, true >(pp, kp, W, ib, w1, b1, w2, b2, ow, ws, sh);
        else       mono_body<false, false>(pp, kp, W, ib, w1, b1, w2, b2, ow, ws, sh);
    }
}

// ============================ host launch ============================
extern "C" void kernel_launch(void* const* d_in, const int* in_sizes, int n_in,
                              void* d_out, int out_size, void* d_ws, size_t ws_size,
                              hipStream_t stream)
{
    const void* pp = d_in[0];
    const int*  kp = (const int*)d_in[1];
    const void* W  = d_in[2];
    const void* ib = d_in[3];
    const void* w1 = d_in[4];
    const int*  b1 = (const int*)d_in[5];
    const void* w2 = d_in[6];
    const int*  b2 = (const int*)d_in[7];
    const void* ow = d_in[8];
    const int*  ob = (const int*)d_in[9];
    int* ws  = (int*)d_ws;
    int* out = (int*)d_out;

    const int B = in_sizes[1] / 2;   // king_positions is (B, 2)
    const int nslots = 2 * B;

    // ws layout (int offsets): [0]=scalar sum, [3]=ticket, partial at +256 ints
    const size_t off_pb = 256;
    const size_t need4 = (off_pb + (size_t)4 * nslots * (NDIM / 2)) * 4;
    const size_t need2 = (off_pb + (size_t)2 * nslots * (NDIM / 2)) * 4;

    int rp = 0;
    if (ws_size >= need4) rp = 4;
    else if (ws_size >= need2) rp = 2;

    if (rp && nslots <= MAXSLOTS) {
        unsigned short* partial = (unsigned short*)(ws + off_pb);
        // grid: 64 kings x rp row-parts x GSTRIDE base groups; blocks loop gi += GSTRIDE
        hipLaunchKernelGGL(nnue_gather, dim3(64 * rp * GSTRIDE), dim3(256), 0, stream,
                           pp, kp, W, partial, ws, nslots, rp);
        hipLaunchKernelGGL(nnue_combine, dim3((B + CPB - 1) / CPB), dim3(256), 0, stream,
                           partial, kp, W, ib, w1, b1, w2, b2, ow, ob, ws, out, nslots, B, rp);
    } else {
        // fallback: monolithic path
        hipLaunchKernelGGL(detect_layout, dim3(1), dim3(1), 0, stream,
                           (const int*)W, (const int*)pp, ws);
        hipLaunchKernelGGL(nnue_mono, dim3(B), dim3(256), 0, stream,
                           pp, kp, W, ib, w1, b1, w2, b2, ow, ws);
        hipLaunchKernelGGL(nnue_finalize, dim3(1), dim3(1), 0, stream, ws, ob, out);
    }
}